// Round 1
// baseline (625.726 us; speedup 1.0000x reference)
//
#include <hip/hip_runtime.h>

// ELBO kernel for the chromatin "Decoding" model.
// Pieces:
//   A) gene_params:   per local gene g (4000): loc=sigmoid(loc_w), rscale=1/scale,
//                     nls=-log(scale)-0.5*log(2pi), lw=logit_w   -> float4[G*32] in ws
//   B) delta matmul:  mixture_delta[n,g,c] = sum_l latent[n,l]*logit_weight[genes_oi[g],l,c]
//                     stored bf16 [N*G*32] in ws (2% tolerance -> bf16 fine)
//   C) histogram:     counts[N*G] uint from local_cellxgene_ix
//   D) cuts:          per cut LSE(t+comp_lp)-LSE(t), no max-subtraction needed (|args|<~10)
//   E) poisson:       counts*log(fe) - fe - lgamma(counts+1), rho computed inline
//   F) finalize:      out[0] = -(sum of block partials)   (d_out is poisoned each launch)

#define TPB 256
#define HALF_LOG_2PI 0.9189385332046727f

static __device__ __forceinline__ unsigned short f2bf(float f) {
  unsigned u = __float_as_uint(f);
  u += 0x7fffu + ((u >> 16) & 1u);   // round-to-nearest-even
  return (unsigned short)(u >> 16);
}
static __device__ __forceinline__ float bf2f(unsigned short h) {
  return __uint_as_float(((unsigned)h) << 16);
}

// 256-thread block reduction; valid in thread 0 only.
static __device__ __forceinline__ float block_reduce(float v) {
  #pragma unroll
  for (int off = 32; off > 0; off >>= 1) v += __shfl_down(v, off, 64);
  __shared__ float wsum[4];
  if ((threadIdx.x & 63) == 0) wsum[threadIdx.x >> 6] = v;
  __syncthreads();
  return (threadIdx.x == 0) ? (wsum[0] + wsum[1] + wsum[2] + wsum[3]) : 0.f;
}

// ---------------- A: gene params ----------------
__global__ __launch_bounds__(TPB) void gene_params_kernel(
    const int* __restrict__ genes_oi,
    const float* __restrict__ loc_w, const float* __restrict__ scale_w,
    const float* __restrict__ logit_w,
    float4* __restrict__ gp, int G) {
  int idx = blockIdx.x * TPB + threadIdx.x;       // over G*32
  if (idx >= G * 32) return;
  int g = idx >> 5, c = idx & 31;
  long long gene = genes_oi[g];
  float lv = loc_w[gene * 32 + c];
  float loc = 1.f / (1.f + __expf(-lv));
  float sc = 1e-5f + __expf(scale_w[gene * 32 + c]);
  gp[idx] = make_float4(loc, 1.f / sc, -__logf(sc) - HALF_LOG_2PI, logit_w[gene * 32 + c]);
}

// ---------------- B: delta matmul ----------------
// block = 256 threads: 16 genes x 16 comp-pairs; each thread: 1 gene, 2 comps, 64 n-rows.
// 8 FMA per ds_read_b128 (wave-uniform LDS broadcast) -> VALU-bound.
__global__ __launch_bounds__(TPB) void delta_kernel(
    const float* __restrict__ latent,        // [N,64]
    const int* __restrict__ genes_oi,        // [G]
    const float* __restrict__ logit_weight,  // [20000,64,32]
    unsigned short* __restrict__ delta,      // bf16 [N*G*32]
    int N, int G) {
  const int cp = threadIdx.x & 15;     // comp pair: c = 2*cp
  const int gl = threadIdx.x >> 4;     // 0..15
  const int g = blockIdx.x * 16 + gl;
  const int n0 = blockIdx.y * 64;
  const int c = cp * 2;

  __shared__ __align__(16) float lat[64][64];   // 16 KB
  for (int t = threadIdx.x; t < 64 * 64; t += TPB) {
    int i = t >> 6, l = t & 63;
    int n = n0 + i;
    lat[i][l] = (n < N) ? latent[(size_t)n * 64 + l] : 0.f;
  }
  __syncthreads();
  if (g >= G) return;

  const long long gene = genes_oi[g];
  const float* wp = logit_weight + gene * 2048 + c;

  float a0[64], a1[64];
  #pragma unroll
  for (int i = 0; i < 64; i++) { a0[i] = 0.f; a1[i] = 0.f; }

  for (int l = 0; l < 64; l += 4) {
    float2 w0 = *(const float2*)(wp + (l + 0) * 32);
    float2 w1 = *(const float2*)(wp + (l + 1) * 32);
    float2 w2 = *(const float2*)(wp + (l + 2) * 32);
    float2 w3 = *(const float2*)(wp + (l + 3) * 32);
    #pragma unroll
    for (int i = 0; i < 64; i++) {
      float4 lv = *(const float4*)(&lat[i][l]);
      a0[i] = fmaf(lv.x, w0.x, a0[i]); a1[i] = fmaf(lv.x, w0.y, a1[i]);
      a0[i] = fmaf(lv.y, w1.x, a0[i]); a1[i] = fmaf(lv.y, w1.y, a1[i]);
      a0[i] = fmaf(lv.z, w2.x, a0[i]); a1[i] = fmaf(lv.z, w2.y, a1[i]);
      a0[i] = fmaf(lv.w, w3.x, a0[i]); a1[i] = fmaf(lv.w, w3.y, a1[i]);
    }
  }

  #pragma unroll 4
  for (int i = 0; i < 64; i++) {
    int n = n0 + i;
    if (n >= N) break;
    size_t off = ((size_t)n * G + g) * 32 + c;
    ushort2 v = make_ushort2(f2bf(a0[i]), f2bf(a1[i]));
    *(ushort2*)(delta + off) = v;
  }
}

// ---------------- C: histogram ----------------
__global__ __launch_bounds__(TPB) void hist_kernel(
    const int* __restrict__ lix, unsigned* __restrict__ counts, int F, long long NG) {
  int i = blockIdx.x * TPB + threadIdx.x;
  if (i >= F) return;
  long long v = lix[i];
  if (v >= 0 && v < NG) atomicAdd(&counts[v], 1u);
}

// ---------------- D: cuts (fast path) ----------------
__global__ __launch_bounds__(TPB) void cuts_kernel(
    const float* __restrict__ xc, const int* __restrict__ gix,
    const int* __restrict__ cxg,
    const float4* __restrict__ gp,            // [G*32]
    const unsigned short* __restrict__ delta, // bf16 [N*G*32]
    float* __restrict__ partials, int K) {
  int k = blockIdx.x * TPB + threadIdx.x;
  float lm = 0.f;
  if (k < K) {
    float x = xc[k];
    int g = gix[k];
    long long ix = cxg[k];
    const float4* gpr = gp + (long long)g * 32;
    const uint4* d4 = (const uint4*)(delta + ix * 32);
    float s1 = 0.f, s2 = 0.f;
    #pragma unroll
    for (int j = 0; j < 4; j++) {
      uint4 q = d4[j];
      unsigned wq[4] = {q.x, q.y, q.z, q.w};
      #pragma unroll
      for (int h = 0; h < 4; h++) {
        int c = j * 8 + h * 2;
        float d0 = __uint_as_float(wq[h] << 16);
        float d1 = __uint_as_float(wq[h] & 0xffff0000u);
        float4 p0 = gpr[c];
        float4 p1 = gpr[c + 1];
        float t0 = p0.w + d0, t1 = p1.w + d1;
        float z0 = (x - p0.x) * p0.y;
        float z1 = (x - p1.x) * p1.y;
        float u0 = t0 + fmaf(-0.5f * z0, z0, p0.z);
        float u1 = t1 + fmaf(-0.5f * z1, z1, p1.z);
        s1 += __expf(u0) + __expf(u1);
        s2 += __expf(t0) + __expf(t1);
      }
    }
    lm = __logf(s1) - __logf(s2);
  }
  float bs = block_reduce(lm);
  if (threadIdx.x == 0) partials[blockIdx.x] = bs;
}

// ---------------- D': cuts fallback (ws too small: delta on the fly) ----------------
__global__ __launch_bounds__(TPB) void cuts_fb_kernel(
    const float* __restrict__ xc, const int* __restrict__ gix,
    const int* __restrict__ cxg,
    const float* __restrict__ latent, const int* __restrict__ genes_oi,
    const float* __restrict__ loc_w, const float* __restrict__ scale_w,
    const float* __restrict__ logit_w, const float* __restrict__ logit_weight,
    float* __restrict__ partials, int K, int G) {
  int k = blockIdx.x * TPB + threadIdx.x;
  float lm = 0.f;
  if (k < K) {
    float x = xc[k];
    int g = gix[k];
    int ix = cxg[k];
    int n_d = ix / G, g_d = ix - n_d * G;
    long long gene_g = genes_oi[g];
    long long gene_d = genes_oi[g_d];
    const float* lw = logit_weight + gene_d * 2048;
    const float* lat = latent + (size_t)n_d * 64;
    float s1 = 0.f, s2 = 0.f;
    for (int c = 0; c < 32; c++) {
      float d = 0.f;
      #pragma unroll 8
      for (int l = 0; l < 64; l++) d = fmaf(lat[l], lw[l * 32 + c], d);
      float loc = 1.f / (1.f + __expf(-loc_w[gene_g * 32 + c]));
      float sc = 1e-5f + __expf(scale_w[gene_g * 32 + c]);
      float t = logit_w[gene_g * 32 + c] + d;
      float z = (x - loc) / sc;
      float u = t + fmaf(-0.5f * z, z, -__logf(sc) - HALF_LOG_2PI);
      s1 += __expf(u);
      s2 += __expf(t);
    }
    lm = __logf(s1) - __logf(s2);
  }
  float bs = block_reduce(lm);
  if (threadIdx.x == 0) partials[blockIdx.x] = bs;
}

// ---------------- E: Poisson fragment counts ----------------
// grid (ceil(G/256), ceil(N/8)); each thread: 1 gene, 8 n-rows.
__global__ __launch_bounds__(TPB) void pois_kernel(
    const float* __restrict__ latent, const int* __restrict__ genes_oi,
    const int* __restrict__ cells_oi,
    const float* __restrict__ rho_weight, const float* __restrict__ rho_bias,
    const float* __restrict__ libsize,
    const unsigned* __restrict__ counts,
    float* __restrict__ partials, int N, int G) {
  int g = blockIdx.x * TPB + threadIdx.x;
  int n0 = blockIdx.y * 8;
  float sum = 0.f;
  if (g < G) {
    long long gene = genes_oi[g];
    const float4* rw = (const float4*)(rho_weight + gene * 64);
    float rho[8];
    #pragma unroll
    for (int j = 0; j < 8; j++) rho[j] = 0.f;
    #pragma unroll
    for (int l4 = 0; l4 < 16; l4++) {
      float4 w = rw[l4];
      #pragma unroll
      for (int j = 0; j < 8; j++) {
        int n = n0 + j;
        if (n < N) {
          float4 lv = *(const float4*)(latent + (size_t)n * 64 + l4 * 4);
          rho[j] += w.x * lv.x + w.y * lv.y + w.z * lv.z + w.w * lv.w;
        }
      }
    }
    float rb = rho_bias[gene];
    #pragma unroll
    for (int j = 0; j < 8; j++) {
      int n = n0 + j;
      if (n >= N) break;
      float lib = libsize[cells_oi[n]];
      float fe = rb * __expf(rho[j]) * lib;
      unsigned cnt = counts[(size_t)n * G + g];
      float term = -fe;
      if (cnt) {
        float lf = 0.f;
        for (unsigned q = 2; q <= cnt; q++) lf += __logf((float)q);
        term += (float)cnt * __logf(fe) - lf;
      }
      sum += term;
    }
  }
  float bs = block_reduce(sum);
  if (threadIdx.x == 0) partials[blockIdx.y * gridDim.x + blockIdx.x] = bs;
}

// ---------------- F: finalize ----------------
__global__ __launch_bounds__(TPB) void finalize_kernel(
    const float* __restrict__ p1, int n1,
    const float* __restrict__ p2, int n2, float* __restrict__ out) {
  float s = 0.f;
  for (int i = threadIdx.x; i < n1; i += TPB) s += p1[i];
  for (int i = threadIdx.x; i < n2; i += TPB) s += p2[i];
  float bs = block_reduce(s);
  if (threadIdx.x == 0) out[0] = -bs;
}

extern "C" void kernel_launch(void* const* d_in, const int* in_sizes, int n_in,
                              void* d_out, int out_size, void* d_ws, size_t ws_size,
                              hipStream_t stream) {
  const int*   lix          = (const int*)d_in[0];
  const float* xc           = (const float*)d_in[1];
  const float* latent       = (const float*)d_in[2];
  const int*   genes_oi     = (const int*)d_in[3];
  const int*   cells_oi     = (const int*)d_in[4];
  const int*   cxg          = (const int*)d_in[5];
  const int*   gix          = (const int*)d_in[6];
  const float* loc_w        = (const float*)d_in[9];
  const float* scale_w      = (const float*)d_in[10];
  const float* logit_w      = (const float*)d_in[11];
  const float* logit_weight = (const float*)d_in[12];
  const float* rho_weight   = (const float*)d_in[13];
  const float* rho_bias     = (const float*)d_in[14];
  const float* libsize      = (const float*)d_in[15];
  float* out = (float*)d_out;

  const int F = in_sizes[0];
  const int K = in_sizes[1];
  const int N = in_sizes[2] / 64;
  const int G = in_sizes[3];
  const long long NG = (long long)N * G;

  const int ncb = (K + TPB - 1) / TPB;
  const int gpx = (G + TPB - 1) / TPB;
  const int npy = (N + 7) / 8;
  const int npb = gpx * npy;

  // fast-path workspace layout
  size_t off = 0;
  auto alloc = [&](size_t bytes) {
    size_t o = off;
    off = (off + bytes + 255) & ~(size_t)255;
    return o;
  };
  size_t delta_off  = alloc((size_t)NG * 32 * 2);   // bf16 delta
  size_t counts_off = alloc((size_t)NG * 4);
  size_t gp_off     = alloc((size_t)G * 32 * 16);
  size_t p1_off     = alloc((size_t)ncb * 4);
  size_t p2_off     = alloc((size_t)npb * 4);
  bool fast = (off <= ws_size);

  char* ws = (char*)d_ws;

  if (fast) {
    unsigned* counts = (unsigned*)(ws + counts_off);
    float4* gp = (float4*)(ws + gp_off);
    unsigned short* delta = (unsigned short*)(ws + delta_off);
    float* p1 = (float*)(ws + p1_off);
    float* p2 = (float*)(ws + p2_off);

    hipMemsetAsync(counts, 0, (size_t)NG * 4, stream);
    gene_params_kernel<<<(G * 32 + TPB - 1) / TPB, TPB, 0, stream>>>(
        genes_oi, loc_w, scale_w, logit_w, gp, G);
    dim3 dgrid((G + 15) / 16, (N + 63) / 64);
    delta_kernel<<<dgrid, TPB, 0, stream>>>(latent, genes_oi, logit_weight, delta, N, G);
    hist_kernel<<<(F + TPB - 1) / TPB, TPB, 0, stream>>>(lix, counts, F, NG);
    cuts_kernel<<<ncb, TPB, 0, stream>>>(xc, gix, cxg, gp, delta, p1, K);
    dim3 pgrid(gpx, npy);
    pois_kernel<<<pgrid, TPB, 0, stream>>>(latent, genes_oi, cells_oi, rho_weight,
                                           rho_bias, libsize, counts, p2, N, G);
    finalize_kernel<<<1, TPB, 0, stream>>>(p1, ncb, p2, npb, out);
  } else {
    // minimal-workspace fallback: counts + partials only; delta computed on the fly
    size_t o2 = 0;
    auto alloc2 = [&](size_t bytes) {
      size_t o = o2;
      o2 = (o2 + bytes + 255) & ~(size_t)255;
      return o;
    };
    size_t c_off  = alloc2((size_t)NG * 4);
    size_t q1_off = alloc2((size_t)ncb * 4);
    size_t q2_off = alloc2((size_t)npb * 4);
    (void)c_off;
    unsigned* counts = (unsigned*)(ws + c_off);
    float* p1 = (float*)(ws + q1_off);
    float* p2 = (float*)(ws + q2_off);

    hipMemsetAsync(counts, 0, (size_t)NG * 4, stream);
    hist_kernel<<<(F + TPB - 1) / TPB, TPB, 0, stream>>>(lix, counts, F, NG);
    cuts_fb_kernel<<<ncb, TPB, 0, stream>>>(xc, gix, cxg, latent, genes_oi, loc_w,
                                            scale_w, logit_w, logit_weight, p1, K, G);
    dim3 pgrid(gpx, npy);
    pois_kernel<<<pgrid, TPB, 0, stream>>>(latent, genes_oi, cells_oi, rho_weight,
                                           rho_bias, libsize, counts, p2, N, G);
    finalize_kernel<<<1, TPB, 0, stream>>>(p1, ncb, p2, npb, out);
  }
}